// Round 10
// baseline (930.488 us; speedup 1.0000x reference)
//
#include <hip/hip_runtime.h>

#define GRP 8
#define SUBD 64
#define NCODE 1024
#define TLEN 4096
#define NBATCH 8
#define NVEC (NBATCH * TLEN)          // 32768
#define QOUT (NBATCH * 512 * TLEN)    // 16777216
#define ROWS 128                      // rows per block
#define NGRPS (NCODE / 8)             // 128 groups of 8 codes

// ws layout (bytes):
// [0]       double lossAcc[2]
// [64]      float e2[2][8][1024]              64 KB
// [65600]   int idx1[8*32768]                 1 MB
// [1114176] float cbP1[8][128][64][8]         2 MB   panel [g][grp][d][8j]
// [3211328] float cbP2[...]                   2 MB
#define WS_E2   64
#define WS_IDX1 (WS_E2 + 65536)
#define WS_P1   (WS_IDX1 + 1048576)
#define WS_P2   (WS_P1 + 2097152)

typedef const __attribute__((address_space(1))) char GCHAR;
typedef __attribute__((address_space(3))) char LCHAR;

__global__ __launch_bounds__(256) void k_e2(const float* __restrict__ cb1,
                                            const float* __restrict__ cb2,
                                            float* __restrict__ e2) {
    int i = blockIdx.x * 256 + threadIdx.x;      // 0 .. 16383
    const float* c = (i < GRP * NCODE) ? (cb1 + (size_t)i * SUBD)
                                       : (cb2 + (size_t)(i - GRP * NCODE) * SUBD);
    float s = 0.f;
#pragma unroll
    for (int d = 0; d < SUBD; ++d) s = __builtin_fmaf(c[d], c[d], s);
    e2[i] = s;
}

// Panel repack (verified r4/r9, absmax 0.0): cbP[g][grp][d][j] = cb[g][grp*8+j][d]
__global__ __launch_bounds__(256) void k_panel(const float* __restrict__ cb1,
                                               const float* __restrict__ cb2,
                                               float* __restrict__ cbP1,
                                               float* __restrict__ cbP2) {
    int i = blockIdx.x * 256 + threadIdx.x;      // 0 .. 16383
    int sel = i >> 13, rest = i & 8191, g = rest >> 10, k = rest & 1023;
    int grp = k >> 3, j = k & 7;
    const float* src = (sel ? cb2 : cb1) + ((size_t)g * NCODE + k) * SUBD;
    float* dst = (sel ? cbP2 : cbP1) + ((size_t)(g * NGRPS + grp) * SUBD) * 8 + j;
#pragma unroll
    for (int s = 0; s < 16; ++s) {
        float4 v = ((const float4*)src)[s];
#pragma unroll
        for (int dd = 0; dd < 4; ++dd) dst[(4 * s + dd) * 8] = ((const float*)&v)[dd];
    }
}

// Block: 256 thr = 4 waves over 128 rows. Wave w owns codes [w*256,(w+1)*256).
// Lane handles TWO rows: (lane) and (lane+64). Codes/e2 are wave-uniform.
// Per d: 1 ds_read2_b32 (2 x values) + 32 uniform code floats + 64 fma.
// Exactness: per (row,code) one ascending-d fma chain; dist = fma(-2,acc,
// fl(x2+e2)); per-lane k ascending, strict <; 4-way merge ascending w
// (= ascending k) with strict < == reference first-index argmin.
template <int STAGE2>
__global__ __launch_bounds__(256, 2) void k_vq(
    const float* __restrict__ x,
    const float* __restrict__ cb1,
    const float* __restrict__ cb2,
    const float* __restrict__ cbP,      // packed panel for search codebook
    const float* __restrict__ e2,       // e2 row for search codebook (8*1024)
    const int* __restrict__ idxPrev,    // idx1 (stage2)
    int* __restrict__ idxOut,           // idx1 (stage1)
    float* __restrict__ outIdxF,
    float* __restrict__ qout,           // stage2
    double* __restrict__ lossAcc)       // stage2
{
    __shared__ __align__(16) float xs[SUBD * ROWS];   // 32 KB [d][row]
    __shared__ float bdH[4 * ROWS];                   // 2 KB
    __shared__ int   biH[4 * ROWS];                   // 2 KB
    __shared__ int   i2s[ROWS];
    __shared__ double wsr[8];

    const int tid = threadIdx.x, w = tid >> 6, lane = tid & 63;
    const int g = blockIdx.y;
    const int row0 = blockIdx.x * ROWS;
    const int bz = row0 / TLEN, t0 = row0 % TLEN;
    const float* xsrc = x + ((size_t)(bz * 512 + g * SUBD)) * TLEN + t0;

    // ---- stage x tile (d-major, linear dest) via global_load_lds (r9 verbatim) ----
    {
#pragma unroll
        for (int q = 0; q < 8; ++q) {
            int inst = w * 8 + q;                 // 0..31, 2 d-rows each
            int d = inst * 2 + (lane >> 5);
            const float* gp = xsrc + (size_t)d * TLEN + (lane & 31) * 4;
            float* lp = xs + inst * 256;          // wave-uniform base
            __builtin_amdgcn_global_load_lds((GCHAR*)gp, (LCHAR*)lp, 16, 0, 0);
        }
    }
    __syncthreads();

    // ---- stage2: residual update + loss1 (256-wide: row=tid&127, hi=tid>>7) ----
    const int rowB = tid & 127, hi = tid >> 7;
    double ls1 = 0.0;
    int i1 = 0;
    if (STAGE2) {
        i1 = idxPrev[g * NVEC + row0 + rowB];
        const float4* z1v = (const float4*)(cb1 + ((size_t)g * NCODE + i1) * SUBD) + hi * 8;
#pragma unroll
        for (int s = 0; s < 8; ++s) {
            float4 z = z1v[s];
#pragma unroll
            for (int dd = 0; dd < 4; ++dd) {
                int d = hi * 32 + s * 4 + dd;
                float r = xs[d * ROWS + rowB];
                float zz = (&z.x)[dd];
                float tt = zz - r;            // fl(z - r)   (loss1 term)
                float zst = r + tt;           // fl(r + tt)
                ls1 += (double)(tt * tt);
                float r2 = r - zst;           // fl(r - zst) -> residual2
                xs[d * ROWS + rowB] = r2;
            }
        }
        __syncthreads();
    }

    // ---- GEMM + argmin: wave w = codes [w*256,(w+1)*256), lane rows (lane, lane+64) ----
    const int w_u = __builtin_amdgcn_readfirstlane(w);

    float x2a = 0.f, x2b = 0.f;
#pragma unroll 8
    for (int d = 0; d < SUBD; ++d) {
        float ra = xs[d * ROWS + lane];
        float rb = xs[d * ROWS + 64 + lane];
        x2a = __builtin_fmaf(ra, ra, x2a);        // ascending-d chains
        x2b = __builtin_fmaf(rb, rb, x2b);
    }

    const float* e2g = e2 + g * NCODE;
    float best[2] = {1e30f, 1e30f};
    int bidx[2] = {0, 0};

    for (int ib = 0; ib < 8; ++ib) {
        const float* cp = cbP + ((size_t)(g * NGRPS) + w_u * 32 + ib * 4) * (SUBD * 8);
        float acc[2][4][8];
#pragma unroll
        for (int r = 0; r < 2; ++r)
#pragma unroll
            for (int gg = 0; gg < 4; ++gg)
#pragma unroll
                for (int j = 0; j < 8; ++j) acc[r][gg][j] = 0.f;

#pragma unroll 2
        for (int d = 0; d < SUBD; ++d) {
            float xa = xs[d * ROWS + lane];
            float xb = xs[d * ROWS + 64 + lane];
#pragma unroll
            for (int gg = 0; gg < 4; ++gg) {
                const float* c8 = cp + gg * (SUBD * 8) + d * 8;
#pragma unroll
                for (int j = 0; j < 8; ++j) {
                    float cv = c8[j];
                    acc[0][gg][j] = __builtin_fmaf(xa, cv, acc[0][gg][j]);   // ascending d
                    acc[1][gg][j] = __builtin_fmaf(xb, cv, acc[1][gg][j]);
                }
            }
        }

#pragma unroll
        for (int gg = 0; gg < 4; ++gg) {
#pragma unroll
            for (int j = 0; j < 8; ++j) {
                int k = w_u * 256 + ib * 32 + gg * 8 + j;
                float ev = e2g[k];
                float tva = x2a + ev;                                // fl(x2 + e2)
                float da = __builtin_fmaf(-2.0f, acc[0][gg][j], tva);// fl(tv - 2a)
                if (da < best[0]) { best[0] = da; bidx[0] = k; }     // ascending k
                float tvb = x2b + ev;
                float db = __builtin_fmaf(-2.0f, acc[1][gg][j], tvb);
                if (db < best[1]) { best[1] = db; bidx[1] = k; }
            }
        }
    }
    bdH[w * ROWS + lane]      = best[0];
    biH[w * ROWS + lane]      = bidx[0];
    bdH[w * ROWS + 64 + lane] = best[1];
    biH[w * ROWS + 64 + lane] = bidx[1];
    __syncthreads();

    // ---- 4-way merge (ascending wave = ascending k; strict <), outputs ----
    if (tid < ROWS) {
        float bd = bdH[tid];
        int   bi = biH[tid];
#pragma unroll
        for (int wv = 1; wv < 4; ++wv) {
            float od = bdH[wv * ROWS + tid];
            int   oi = biH[wv * ROWS + tid];
            if (od < bd) { bd = od; bi = oi; }
        }
        int nv = row0 + tid;
        outIdxF[(size_t)g * NVEC + nv] = (float)bi;
        if (!STAGE2) idxOut[g * NVEC + nv] = bi;
        else i2s[tid] = bi;
    }

    // ---- stage2 fused epilogue: output + loss2 (verbatim exprs) ----
    double ls2 = 0.0;
    if (STAGE2) {
        __syncthreads();
        int bi = i2s[rowB];
        const float4* z1v = (const float4*)(cb1 + ((size_t)g * NCODE + i1) * SUBD) + hi * 8;
        const float4* z2v = (const float4*)(cb2 + ((size_t)g * NCODE + bi) * SUBD) + hi * 8;
        const float* xp = xsrc + rowB;
        float* op = qout + ((size_t)(bz * 512 + g * SUBD)) * TLEN + t0 + rowB;
#pragma unroll
        for (int s = 0; s < 8; ++s) {
            float4 z1 = z1v[s];
            float4 z2 = z2v[s];
#pragma unroll
            for (int dd = 0; dd < 4; ++dd) {
                int d = hi * 32 + s * 4 + dd;
                float xv = xp[(size_t)d * TLEN];
                float r2 = xs[d * ROWS + rowB];     // residual2 (bit-exact)
                float z1f = (&z1.x)[dd];
                float z2f = (&z2.x)[dd];
                float t1 = z1f - xv;
                float zst1 = xv + t1;
                float t2 = z2f - r2;                // fl(z2 - r2) (loss2)
                float zst2 = r2 + t2;
                float qv = zst1 + zst2;             // fl(zst1 + zst2)
                op[(size_t)d * TLEN] = qv;
                ls2 += (double)(t2 * t2);
            }
        }

        // block reduce both losses, 2 atomics per block
#pragma unroll
        for (int off = 32; off; off >>= 1) {
            ls1 += __shfl_down(ls1, off, 64);
            ls2 += __shfl_down(ls2, off, 64);
        }
        if (lane == 0) { wsr[w] = ls1; wsr[4 + w] = ls2; }
        __syncthreads();
        if (tid == 0)
            atomicAdd(lossAcc + 0, wsr[0] + wsr[1] + wsr[2] + wsr[3]);
        else if (tid == 64)
            atomicAdd(lossAcc + 1, wsr[4] + wsr[5] + wsr[6] + wsr[7]);
    }
}

__global__ void k_final(float* __restrict__ lossOut, const double* __restrict__ lossAcc) {
    // loss_i = 1.25 * mean_i ; total = (l1+l2)/2 = 0.625*(m1+m2)
    double m = (lossAcc[0] + lossAcc[1]) / (double)QOUT;
    lossOut[0] = (float)(0.625 * m);
}

extern "C" void kernel_launch(void* const* d_in, const int* in_sizes, int n_in,
                              void* d_out, int out_size, void* d_ws, size_t ws_size,
                              hipStream_t stream) {
    const float* x   = (const float*)d_in[0];
    const float* cb1 = (const float*)d_in[1];
    const float* cb2 = (const float*)d_in[2];
    float* out = (float*)d_out;

    char* ws = (char*)d_ws;
    double* lossAcc = (double*)ws;
    float* e2   = (float*)(ws + WS_E2);
    int*   idx1 = (int*)(ws + WS_IDX1);
    float* cbP1 = (float*)(ws + WS_P1);
    float* cbP2 = (float*)(ws + WS_P2);

    hipMemsetAsync(ws, 0, 16, stream);

    k_e2<<<dim3(64), dim3(256), 0, stream>>>(cb1, cb2, e2);
    k_panel<<<dim3(64), dim3(256), 0, stream>>>(cb1, cb2, cbP1, cbP2);

    dim3 grid(NVEC / ROWS, GRP);                           // (256, 8)
    float* outIdx = out + QOUT + 1;
    k_vq<0><<<grid, dim3(256), 0, stream>>>(x, cb1, cb2, cbP1, e2,
                                            nullptr, idx1, outIdx, nullptr, nullptr);
    k_vq<1><<<grid, dim3(256), 0, stream>>>(x, cb1, cb2, cbP2, e2 + GRP * NCODE,
                                            idx1, nullptr, outIdx + (size_t)GRP * NVEC,
                                            out, lossAcc);
    k_final<<<1, 1, 0, stream>>>(out + QOUT, lossAcc);
}

// Round 11
// 762.341 us; speedup vs baseline: 1.2206x; 1.2206x over previous
//
#include <hip/hip_runtime.h>

#define GRP 8
#define SUBD 64
#define NCODE 1024
#define TLEN 4096
#define NBATCH 8
#define NVEC (NBATCH * TLEN)          // 32768
#define QOUT (NBATCH * 512 * TLEN)    // 16777216
#define ROWS 128                      // rows per block
#define NGRPS (NCODE / 8)             // 128 groups of 8 codes

// ws layout (bytes):
// [0]       double lossAcc[2]
// [64]      float e2[2][8][1024]              64 KB
// [65600]   int idx1[8*32768]                 1 MB
// [1114176] float cbP1[8][128][64][8]         2 MB   panel [g][grp][d][8j]
// [3211328] float cbP2[...]                   2 MB
#define WS_E2   64
#define WS_IDX1 (WS_E2 + 65536)
#define WS_P1   (WS_IDX1 + 1048576)
#define WS_P2   (WS_P1 + 2097152)

typedef const __attribute__((address_space(1))) char GCHAR;
typedef __attribute__((address_space(3))) char LCHAR;
typedef float f2 __attribute__((ext_vector_type(2)));

__global__ __launch_bounds__(256) void k_e2(const float* __restrict__ cb1,
                                            const float* __restrict__ cb2,
                                            float* __restrict__ e2) {
    int i = blockIdx.x * 256 + threadIdx.x;      // 0 .. 16383
    const float* c = (i < GRP * NCODE) ? (cb1 + (size_t)i * SUBD)
                                       : (cb2 + (size_t)(i - GRP * NCODE) * SUBD);
    float s = 0.f;
#pragma unroll
    for (int d = 0; d < SUBD; ++d) s = __builtin_fmaf(c[d], c[d], s);
    e2[i] = s;
}

// Panel repack (verified r4/r9/r10, absmax 0.0): cbP[g][grp][d][j] = cb[g][grp*8+j][d]
__global__ __launch_bounds__(256) void k_panel(const float* __restrict__ cb1,
                                               const float* __restrict__ cb2,
                                               float* __restrict__ cbP1,
                                               float* __restrict__ cbP2) {
    int i = blockIdx.x * 256 + threadIdx.x;      // 0 .. 16383
    int sel = i >> 13, rest = i & 8191, g = rest >> 10, k = rest & 1023;
    int grp = k >> 3, j = k & 7;
    const float* src = (sel ? cb2 : cb1) + ((size_t)g * NCODE + k) * SUBD;
    float* dst = (sel ? cbP2 : cbP1) + ((size_t)(g * NGRPS + grp) * SUBD) * 8 + j;
#pragma unroll
    for (int s = 0; s < 16; ++s) {
        float4 v = ((const float4*)src)[s];
#pragma unroll
        for (int dd = 0; dd < 4; ++dd) dst[(4 * s + dd) * 8] = ((const float*)&v)[dd];
    }
}

// Block: 256 thr = 4 waves over 128 rows. Wave w owns codes [w*256,(w+1)*256).
// Lane handles rows (2*lane, 2*lane+1) -> one ds_read_b64 per d.
// Inner loop: float2 fma over CODE PAIRS -> v_pk_fma_f32 (2 exact fp32 FMA /
// instr); each acc element keeps its own ascending-d chain (bit-exact).
// Exactness: dist = fma(-2,acc,fl(x2+e2)); per-lane k ascending, strict <;
// 4-way merge ascending w (= ascending k) with strict < == first-index argmin.
template <int STAGE2>
__global__ __launch_bounds__(256, 3) void k_vq(
    const float* __restrict__ x,
    const float* __restrict__ cb1,
    const float* __restrict__ cb2,
    const float* __restrict__ cbP,      // packed panel for search codebook
    const float* __restrict__ e2,       // e2 row for search codebook (8*1024)
    const int* __restrict__ idxPrev,    // idx1 (stage2)
    int* __restrict__ idxOut,           // idx1 (stage1)
    float* __restrict__ outIdxF,
    float* __restrict__ qout,           // stage2
    double* __restrict__ lossAcc)       // stage2
{
    __shared__ __align__(16) float xs[SUBD * ROWS];   // 32 KB [d][row]
    __shared__ float bdH[4 * ROWS];                   // 2 KB
    __shared__ int   biH[4 * ROWS];                   // 2 KB
    __shared__ int   i2s[ROWS];
    __shared__ double wsr[8];

    const int tid = threadIdx.x, w = tid >> 6, lane = tid & 63;
    const int g = blockIdx.y;
    const int row0 = blockIdx.x * ROWS;
    const int bz = row0 / TLEN, t0 = row0 % TLEN;
    const float* xsrc = x + ((size_t)(bz * 512 + g * SUBD)) * TLEN + t0;

    // ---- stage x tile (d-major, linear dest) via global_load_lds ----
    {
#pragma unroll
        for (int q = 0; q < 8; ++q) {
            int inst = w * 8 + q;                 // 0..31, 2 d-rows each
            int d = inst * 2 + (lane >> 5);
            const float* gp = xsrc + (size_t)d * TLEN + (lane & 31) * 4;
            float* lp = xs + inst * 256;          // wave-uniform base
            __builtin_amdgcn_global_load_lds((GCHAR*)gp, (LCHAR*)lp, 16, 0, 0);
        }
    }
    __syncthreads();

    // ---- stage2: residual update + loss1 (256-wide: row=tid&127, hi=tid>>7) ----
    const int rowB = tid & 127, hi = tid >> 7;
    double ls1 = 0.0;
    int i1 = 0;
    if (STAGE2) {
        i1 = idxPrev[g * NVEC + row0 + rowB];
        const float4* z1v = (const float4*)(cb1 + ((size_t)g * NCODE + i1) * SUBD) + hi * 8;
#pragma unroll
        for (int s = 0; s < 8; ++s) {
            float4 z = z1v[s];
#pragma unroll
            for (int dd = 0; dd < 4; ++dd) {
                int d = hi * 32 + s * 4 + dd;
                float r = xs[d * ROWS + rowB];
                float zz = (&z.x)[dd];
                float tt = zz - r;            // fl(z - r)   (loss1 term)
                float zst = r + tt;           // fl(r + tt)
                ls1 += (double)(tt * tt);
                float r2 = r - zst;           // fl(r - zst) -> residual2
                xs[d * ROWS + rowB] = r2;
            }
        }
        __syncthreads();
    }

    // ---- GEMM + argmin: wave w = codes [w*256,(w+1)*256), lane rows (2l, 2l+1) ----
    const int w_u = __builtin_amdgcn_readfirstlane(w);
    const int ra_row = 2 * lane, rb_row = 2 * lane + 1;

    float x2a = 0.f, x2b = 0.f;
#pragma unroll 8
    for (int d = 0; d < SUBD; ++d) {
        float ra = xs[d * ROWS + ra_row];
        float rb = xs[d * ROWS + rb_row];
        x2a = __builtin_fmaf(ra, ra, x2a);        // ascending-d chains
        x2b = __builtin_fmaf(rb, rb, x2b);
    }

    const float* e2g = e2 + g * NCODE;
    float best[2] = {1e30f, 1e30f};
    int bidx[2] = {0, 0};

    for (int ib = 0; ib < 8; ++ib) {
        const float* cp = cbP + ((size_t)(g * NGRPS) + w_u * 32 + ib * 4) * (SUBD * 8);
        f2 acc[2][4][4];                          // [row][grp][code-pair]
#pragma unroll
        for (int r = 0; r < 2; ++r)
#pragma unroll
            for (int gg = 0; gg < 4; ++gg)
#pragma unroll
                for (int p = 0; p < 4; ++p) acc[r][gg][p] = (f2){0.f, 0.f};

#pragma unroll 2
        for (int d = 0; d < SUBD; ++d) {
            float xa = xs[d * ROWS + ra_row];
            float xb = xs[d * ROWS + rb_row];
            f2 xa2 = {xa, xa}, xb2 = {xb, xb};
#pragma unroll
            for (int gg = 0; gg < 4; ++gg) {
                const f2* c2 = (const f2*)(cp + gg * (SUBD * 8) + d * 8);
#pragma unroll
                for (int p = 0; p < 4; ++p) {
                    f2 cv = c2[p];
                    acc[0][gg][p] = __builtin_elementwise_fma(xa2, cv, acc[0][gg][p]);
                    acc[1][gg][p] = __builtin_elementwise_fma(xb2, cv, acc[1][gg][p]);
                }
            }
        }

#pragma unroll
        for (int gg = 0; gg < 4; ++gg) {
#pragma unroll
            for (int p = 0; p < 4; ++p) {
#pragma unroll
                for (int h = 0; h < 2; ++h) {
                    int k = w_u * 256 + ib * 32 + gg * 8 + 2 * p + h;    // ascending
                    float ev = e2g[k];
                    float tva = x2a + ev;                                // fl(x2 + e2)
                    float da = __builtin_fmaf(-2.0f, acc[0][gg][p][h], tva);
                    if (da < best[0]) { best[0] = da; bidx[0] = k; }
                    float tvb = x2b + ev;
                    float db = __builtin_fmaf(-2.0f, acc[1][gg][p][h], tvb);
                    if (db < best[1]) { best[1] = db; bidx[1] = k; }
                }
            }
        }
    }
    bdH[w * ROWS + ra_row] = best[0];
    biH[w * ROWS + ra_row] = bidx[0];
    bdH[w * ROWS + rb_row] = best[1];
    biH[w * ROWS + rb_row] = bidx[1];
    __syncthreads();

    // ---- 4-way merge (ascending wave = ascending k; strict <), outputs ----
    if (tid < ROWS) {
        float bd = bdH[tid];
        int   bi = biH[tid];
#pragma unroll
        for (int wv = 1; wv < 4; ++wv) {
            float od = bdH[wv * ROWS + tid];
            int   oi = biH[wv * ROWS + tid];
            if (od < bd) { bd = od; bi = oi; }
        }
        int nv = row0 + tid;
        outIdxF[(size_t)g * NVEC + nv] = (float)bi;
        if (!STAGE2) idxOut[g * NVEC + nv] = bi;
        else i2s[tid] = bi;
    }

    // ---- stage2 fused epilogue: output + loss2 (verbatim exprs) ----
    double ls2 = 0.0;
    if (STAGE2) {
        __syncthreads();
        int bi = i2s[rowB];
        const float4* z1v = (const float4*)(cb1 + ((size_t)g * NCODE + i1) * SUBD) + hi * 8;
        const float4* z2v = (const float4*)(cb2 + ((size_t)g * NCODE + bi) * SUBD) + hi * 8;
        const float* xp = xsrc + rowB;
        float* op = qout + ((size_t)(bz * 512 + g * SUBD)) * TLEN + t0 + rowB;
#pragma unroll
        for (int s = 0; s < 8; ++s) {
            float4 z1 = z1v[s];
            float4 z2 = z2v[s];
#pragma unroll
            for (int dd = 0; dd < 4; ++dd) {
                int d = hi * 32 + s * 4 + dd;
                float xv = xp[(size_t)d * TLEN];
                float r2 = xs[d * ROWS + rowB];     // residual2 (bit-exact)
                float z1f = (&z1.x)[dd];
                float z2f = (&z2.x)[dd];
                float t1 = z1f - xv;
                float zst1 = xv + t1;
                float t2 = z2f - r2;                // fl(z2 - r2) (loss2)
                float zst2 = r2 + t2;
                float qv = zst1 + zst2;             // fl(zst1 + zst2)
                op[(size_t)d * TLEN] = qv;
                ls2 += (double)(t2 * t2);
            }
        }

        // block reduce both losses, 2 atomics per block
#pragma unroll
        for (int off = 32; off; off >>= 1) {
            ls1 += __shfl_down(ls1, off, 64);
            ls2 += __shfl_down(ls2, off, 64);
        }
        if (lane == 0) { wsr[w] = ls1; wsr[4 + w] = ls2; }
        __syncthreads();
        if (tid == 0)
            atomicAdd(lossAcc + 0, wsr[0] + wsr[1] + wsr[2] + wsr[3]);
        else if (tid == 64)
            atomicAdd(lossAcc + 1, wsr[4] + wsr[5] + wsr[6] + wsr[7]);
    }
}

__global__ void k_final(float* __restrict__ lossOut, const double* __restrict__ lossAcc) {
    // loss_i = 1.25 * mean_i ; total = (l1+l2)/2 = 0.625*(m1+m2)
    double m = (lossAcc[0] + lossAcc[1]) / (double)QOUT;
    lossOut[0] = (float)(0.625 * m);
}

extern "C" void kernel_launch(void* const* d_in, const int* in_sizes, int n_in,
                              void* d_out, int out_size, void* d_ws, size_t ws_size,
                              hipStream_t stream) {
    const float* x   = (const float*)d_in[0];
    const float* cb1 = (const float*)d_in[1];
    const float* cb2 = (const float*)d_in[2];
    float* out = (float*)d_out;

    char* ws = (char*)d_ws;
    double* lossAcc = (double*)ws;
    float* e2   = (float*)(ws + WS_E2);
    int*   idx1 = (int*)(ws + WS_IDX1);
    float* cbP1 = (float*)(ws + WS_P1);
    float* cbP2 = (float*)(ws + WS_P2);

    hipMemsetAsync(ws, 0, 16, stream);

    k_e2<<<dim3(64), dim3(256), 0, stream>>>(cb1, cb2, e2);
    k_panel<<<dim3(64), dim3(256), 0, stream>>>(cb1, cb2, cbP1, cbP2);

    dim3 grid(NVEC / ROWS, GRP);                           // (256, 8)
    float* outIdx = out + QOUT + 1;
    k_vq<0><<<grid, dim3(256), 0, stream>>>(x, cb1, cb2, cbP1, e2,
                                            nullptr, idx1, outIdx, nullptr, nullptr);
    k_vq<1><<<grid, dim3(256), 0, stream>>>(x, cb1, cb2, cbP2, e2 + GRP * NCODE,
                                            idx1, nullptr, outIdx + (size_t)GRP * NVEC,
                                            out, lossAcc);
    k_final<<<1, 1, 0, stream>>>(out + QOUT, lossAcc);
}